// Round 8
// baseline (130.782 us; speedup 1.0000x reference)
//
#include <hip/hip_runtime.h>

#define S_DIM 16
#define B_DIM 512
#define H_DIM 2048
#define EPS 1e-8f

typedef short bf16x8 __attribute__((ext_vector_type(8)));
typedef float f32x4 __attribute__((ext_vector_type(4)));
typedef float f32x16 __attribute__((ext_vector_type(16)));

__device__ __forceinline__ unsigned short f2bf(float f) {
    union { float f; unsigned int u; } v; v.f = f;
    unsigned int u = v.u;
    unsigned int r = (u + 0x7fffu + ((u >> 16) & 1u)) >> 16;
    return (unsigned short)r;
}

__device__ __forceinline__ float dot4(const float4& a, const float4& b) {
    return a.x*b.x + a.y*b.y + a.z*b.z + a.w*b.w;
}

// ---------------- Kernel 1: sims + weighted mean -> wRep (bf16), fused W->bf16 ----------------
// (R5 best, verbatim: dual-row per wave, OG in LDS, E read once, W tail)
__global__ __launch_bounds__(512, 4) void simwrep_kernel(
    const float* __restrict__ OG, const float* __restrict__ E,
    const float* __restrict__ W, unsigned short* __restrict__ wrep,
    unsigned short* __restrict__ Wb) {
    const int b = blockIdx.x;
    const int t = threadIdx.x;
    const int lane = t & 63;
    const int wave = t >> 6;

    __shared__ float4 ogs[512];      // 8 KiB
    __shared__ float4 buf[8][512];   // 64 KiB
    __shared__ float red[8];

    const float4* og4 = (const float4*)(OG + (size_t)b * H_DIM);
    float4 o = og4[t];
    ogs[t] = o;
    float p = dot4(o, o);
    #pragma unroll
    for (int m = 32; m >= 1; m >>= 1) p += __shfl_xor(p, m, 64);
    if (lane == 0) red[wave] = p;
    __syncthreads();
    float og2 = 0.f;
    #pragma unroll
    for (int w = 0; w < 8; ++w) og2 += red[w];
    const float onorm = sqrtf(og2);

    const float4* e4a = (const float4*)(E + ((size_t)wave * B_DIM + b) * H_DIM);
    const float4* e4b = (const float4*)(E + ((size_t)(wave + 8) * B_DIM + b) * H_DIM);
    float4 ea[8], eb[8];
    #pragma unroll
    for (int i = 0; i < 8; ++i) {
        ea[i] = e4a[i * 64 + lane];
        eb[i] = e4b[i * 64 + lane];
    }
    float da = 0.f, na = 0.f, db = 0.f, nb = 0.f;
    #pragma unroll
    for (int i = 0; i < 8; ++i) {
        float4 og = ogs[i * 64 + lane];
        da += dot4(ea[i], og);
        na += dot4(ea[i], ea[i]);
        db += dot4(eb[i], og);
        nb += dot4(eb[i], eb[i]);
    }
    #pragma unroll
    for (int m = 32; m >= 1; m >>= 1) {
        da += __shfl_xor(da, m, 64);
        na += __shfl_xor(na, m, 64);
        db += __shfl_xor(db, m, 64);
        nb += __shfl_xor(nb, m, 64);
    }
    const float sima = da / fmaxf(sqrtf(na) * onorm, EPS);
    const float simb = db / fmaxf(sqrtf(nb) * onorm, EPS);

    #pragma unroll
    for (int i = 0; i < 8; ++i) {
        float4 v;
        v.x = ea[i].x * sima + eb[i].x * simb;
        v.y = ea[i].y * sima + eb[i].y * simb;
        v.z = ea[i].z * sima + eb[i].z * simb;
        v.w = ea[i].w * sima + eb[i].w * simb;
        buf[wave][i * 64 + lane] = v;
    }
    __syncthreads();

    float4 s = buf[0][t];
    #pragma unroll
    for (int w = 1; w < 8; ++w) {
        float4 v = buf[w][t];
        s.x += v.x; s.y += v.y; s.z += v.z; s.w += v.w;
    }
    const float sc = 1.f / (float)S_DIM;
    ushort4 ob;
    ob.x = f2bf(s.x * sc); ob.y = f2bf(s.y * sc);
    ob.z = f2bf(s.z * sc); ob.w = f2bf(s.w * sc);
    ((ushort4*)wrep)[(size_t)b * (H_DIM / 4) + t] = ob;

    const float4* w4 = (const float4*)W;
    #pragma unroll
    for (int j = 0; j < 4; ++j) {
        const size_t idx = (size_t)b * 2048 + j * 512 + t;
        float4 v = w4[idx];
        ushort4 c;
        c.x = f2bf(v.x); c.y = f2bf(v.y); c.z = f2bf(v.z); c.w = f2bf(v.w);
        ((ushort4*)Wb)[idx] = c;
    }
}

// ---------------- Kernel 2: out = wRep @ Wb^T + b  (32x32x16 MFMA, K-split) ----------------
// 64(M)x32(N) block tile, grid (64,8)=512 blocks = 2/CU. 4 waves: wave w ->
// M-half mh=w>>1, K-half kh=w&1; each computes a 32x32 partial over K=1024 via
// mfma_f32_32x32x16_bf16 (2x MACs per LDS fragment byte vs 16x16x32).
// LDS K-slab layout: A short idx (g*64+row)*8, g=chunk*4+(k8 within K32);
// B at 4096 + (g*32+row)*8. Frag reads are contiguous per half-wave (no
// conflicts, no pad). Per iter stages K32 of BOTH K-halves. Register prefetch.
// Epilogue: kh=1 waves dump acc to LDS; kh=0 waves merge + bias + store.
__global__ __launch_bounds__(256) void gemm_kernel(
    const unsigned short* __restrict__ A, const unsigned short* __restrict__ Wb,
    const float* __restrict__ bias, float* __restrict__ out) {
    const int n0 = blockIdx.x * 32;
    const int m0 = blockIdx.y * 64;

    __shared__ __align__(16) unsigned short lds[6144];   // 12 KiB

    const int t = threadIdx.x;
    const int lane = t & 63;
    const int wave = t >> 6;
    const int kh = wave & 1;    // K-half
    const int mh = wave >> 1;   // M-half

    // A staging: 8 KiB/iter. thread t: row=t>>2, chunk=(t>>1)&1, h16=t&1 (16 shorts).
    const int ar = t >> 2;
    const int ac = (t >> 1) & 1;
    const int ah = t & 1;
    const unsigned short* apg = A + (size_t)(m0 + ar) * H_DIM + ac * 1024 + ah * 16;
    unsigned short* al0 = &lds[(((ac * 4 + ah * 2 + 0) * 64) + ar) * 8];
    unsigned short* al1 = &lds[(((ac * 4 + ah * 2 + 1) * 64) + ar) * 8];
    // B staging: 4 KiB/iter. thread t: row=t>>3, g=t&7 (8 shorts).
    const int br = t >> 3;
    const int bg = t & 7;
    const unsigned short* bpg = Wb + (size_t)(n0 + br) * H_DIM + (bg >> 2) * 1024 + (bg & 3) * 8;
    unsigned short* bl = &lds[4096 + (bg * 32 + br) * 8];

    f32x16 acc = {0.f,0.f,0.f,0.f, 0.f,0.f,0.f,0.f, 0.f,0.f,0.f,0.f, 0.f,0.f,0.f,0.f};

    const int hw = lane >> 5;       // half-wave
    const int l31 = lane & 31;

    uint4 av0 = *(const uint4*)(apg);
    uint4 av1 = *(const uint4*)(apg + 8);
    uint4 bv  = *(const uint4*)(bpg);

    for (int ki = 0; ki < 32; ++ki) {
        *(uint4*)al0 = av0;
        *(uint4*)al1 = av1;
        *(uint4*)bl  = bv;
        __syncthreads();
        if (ki + 1 < 32) {   // register prefetch of next K32-per-half
            av0 = *(const uint4*)(apg + (ki + 1) * 32);
            av1 = *(const uint4*)(apg + (ki + 1) * 32 + 8);
            bv  = *(const uint4*)(bpg + (ki + 1) * 32);
        }
        #pragma unroll
        for (int ks = 0; ks < 2; ++ks) {
            const int g = kh * 4 + ks * 2 + hw;
            bf16x8 af = *(const bf16x8*)&lds[(g * 64 + mh * 32 + l31) * 8];
            bf16x8 bf = *(const bf16x8*)&lds[4096 + (g * 32 + l31) * 8];
            acc = __builtin_amdgcn_mfma_f32_32x32x16_bf16(af, bf, acc, 0, 0, 0);
        }
        __syncthreads();
    }

    // Merge K-halves. C/D mapping: col=lane&31, row=(reg&3)+8*(reg>>2)+4*(lane>>5)
    float* red = (float*)lds;   // 2 slabs x 1024 f32 = 8 KiB
    if (kh == 1) {
        #pragma unroll
        for (int r = 0; r < 16; ++r) {
            const int orow = (r & 3) + 8 * (r >> 2) + 4 * hw;
            red[mh * 1024 + orow * 32 + l31] = acc[r];
        }
    }
    __syncthreads();
    if (kh == 0) {
        const float b0 = bias[n0 + l31];
        #pragma unroll
        for (int r = 0; r < 16; ++r) {
            const int orow = (r & 3) + 8 * (r >> 2) + 4 * hw;
            out[(size_t)(m0 + mh * 32 + orow) * H_DIM + n0 + l31] =
                acc[r] + red[mh * 1024 + orow * 32 + l31] + b0;
        }
    }
}

extern "C" void kernel_launch(void* const* d_in, const int* in_sizes, int n_in,
                              void* d_out, int out_size, void* d_ws, size_t ws_size,
                              hipStream_t stream) {
    const float* OG   = (const float*)d_in[0];
    const float* E    = (const float*)d_in[1];
    const float* W    = (const float*)d_in[2];
    const float* bias = (const float*)d_in[3];
    float* out = (float*)d_out;

    unsigned short* wrep = (unsigned short*)d_ws;                 // 2 MiB bf16
    unsigned short* Wb   = wrep + (size_t)B_DIM * H_DIM;          // 8 MiB bf16

    simwrep_kernel<<<B_DIM, 512, 0, stream>>>(OG, E, W, wrep, Wb);
    gemm_kernel<<<dim3(H_DIM / 32, B_DIM / 64), 256, 0, stream>>>(wrep, Wb, bias, out);
}

// Round 9
// 124.133 us; speedup vs baseline: 1.0536x; 1.0536x over previous
//
#include <hip/hip_runtime.h>

#define S_DIM 16
#define B_DIM 512
#define H_DIM 2048
#define EPS 1e-8f

typedef short bf16x8 __attribute__((ext_vector_type(8)));
typedef float f32x4 __attribute__((ext_vector_type(4)));

__device__ __forceinline__ unsigned short f2bf(float f) {
    union { float f; unsigned int u; } v; v.f = f;
    unsigned int u = v.u;
    unsigned int r = (u + 0x7fffu + ((u >> 16) & 1u)) >> 16;
    return (unsigned short)r;
}

__device__ __forceinline__ float dot4(const float4& a, const float4& b) {
    return a.x*b.x + a.y*b.y + a.z*b.z + a.w*b.w;
}

// ---------------- Kernel 1: sims + weighted mean -> wRep (bf16), fused W->bf16 ----------------
// (R5 best, verbatim: dual-row per wave, OG in LDS, E read once, W tail)
__global__ __launch_bounds__(512, 4) void simwrep_kernel(
    const float* __restrict__ OG, const float* __restrict__ E,
    const float* __restrict__ W, unsigned short* __restrict__ wrep,
    unsigned short* __restrict__ Wb) {
    const int b = blockIdx.x;
    const int t = threadIdx.x;
    const int lane = t & 63;
    const int wave = t >> 6;

    __shared__ float4 ogs[512];      // 8 KiB
    __shared__ float4 buf[8][512];   // 64 KiB
    __shared__ float red[8];

    const float4* og4 = (const float4*)(OG + (size_t)b * H_DIM);
    float4 o = og4[t];
    ogs[t] = o;
    float p = dot4(o, o);
    #pragma unroll
    for (int m = 32; m >= 1; m >>= 1) p += __shfl_xor(p, m, 64);
    if (lane == 0) red[wave] = p;
    __syncthreads();
    float og2 = 0.f;
    #pragma unroll
    for (int w = 0; w < 8; ++w) og2 += red[w];
    const float onorm = sqrtf(og2);

    const float4* e4a = (const float4*)(E + ((size_t)wave * B_DIM + b) * H_DIM);
    const float4* e4b = (const float4*)(E + ((size_t)(wave + 8) * B_DIM + b) * H_DIM);
    float4 ea[8], eb[8];
    #pragma unroll
    for (int i = 0; i < 8; ++i) {
        ea[i] = e4a[i * 64 + lane];
        eb[i] = e4b[i * 64 + lane];
    }
    float da = 0.f, na = 0.f, db = 0.f, nb = 0.f;
    #pragma unroll
    for (int i = 0; i < 8; ++i) {
        float4 og = ogs[i * 64 + lane];
        da += dot4(ea[i], og);
        na += dot4(ea[i], ea[i]);
        db += dot4(eb[i], og);
        nb += dot4(eb[i], eb[i]);
    }
    #pragma unroll
    for (int m = 32; m >= 1; m >>= 1) {
        da += __shfl_xor(da, m, 64);
        na += __shfl_xor(na, m, 64);
        db += __shfl_xor(db, m, 64);
        nb += __shfl_xor(nb, m, 64);
    }
    const float sima = da / fmaxf(sqrtf(na) * onorm, EPS);
    const float simb = db / fmaxf(sqrtf(nb) * onorm, EPS);

    #pragma unroll
    for (int i = 0; i < 8; ++i) {
        float4 v;
        v.x = ea[i].x * sima + eb[i].x * simb;
        v.y = ea[i].y * sima + eb[i].y * simb;
        v.z = ea[i].z * sima + eb[i].z * simb;
        v.w = ea[i].w * sima + eb[i].w * simb;
        buf[wave][i * 64 + lane] = v;
    }
    __syncthreads();

    float4 s = buf[0][t];
    #pragma unroll
    for (int w = 1; w < 8; ++w) {
        float4 v = buf[w][t];
        s.x += v.x; s.y += v.y; s.z += v.z; s.w += v.w;
    }
    const float sc = 1.f / (float)S_DIM;
    ushort4 ob;
    ob.x = f2bf(s.x * sc); ob.y = f2bf(s.y * sc);
    ob.z = f2bf(s.z * sc); ob.w = f2bf(s.w * sc);
    ((ushort4*)wrep)[(size_t)b * (H_DIM / 4) + t] = ob;

    const float4* w4 = (const float4*)W;
    #pragma unroll
    for (int j = 0; j < 4; ++j) {
        const size_t idx = (size_t)b * 2048 + j * 512 + t;
        float4 v = w4[idx];
        ushort4 c;
        c.x = f2bf(v.x); c.y = f2bf(v.y); c.z = f2bf(v.z); c.w = f2bf(v.w);
        ((ushort4*)Wb)[idx] = c;
    }
}

// ---------------- Kernel 2: out = wRep @ Wb^T + b  (bf16 MFMA, fp32 acc) ----------------
// R5 structure (64x32 tile, BK=64, 512 blocks = 2/CU, 4 waves each 32x16 via two
// independent acc chains of 16x16x32) with DOUBLE-BUFFERED LDS: write tile k+1
// into buf^1 while computing from buf^0 -> ONE barrier per iteration (33 total
// vs 64), and the global prefetch only has to land before the ds_write at the
// END of the iteration (not before the MFMA phase) -> latency hidden.
__global__ __launch_bounds__(256) void gemm_kernel(
    const unsigned short* __restrict__ A, const unsigned short* __restrict__ Wb,
    const float* __restrict__ bias, float* __restrict__ out) {
    const int n0 = blockIdx.x * 32;
    const int m0 = blockIdx.y * 64;

    __shared__ unsigned short As[2][64][72];  // 2 x 9 KiB (+8 pad)
    __shared__ unsigned short Ws[2][32][72];  // 2 x 4.5 KiB

    const int t = threadIdx.x;
    const int lane = t & 63;
    const int wave = t >> 6;
    const int wm = (wave & 1) * 32;
    const int wn = (wave >> 1) * 16;

    const int lrA = t >> 2, lqA = t & 3;   // A: 4 thr/row, 32 shorts each
    const int lrB = t >> 3, lqB = t & 7;   // Ws: 8 thr/row, 8 shorts each

    const unsigned short* ap = A + (size_t)(m0 + lrA) * H_DIM + lqA * 16;
    const unsigned short* bp = Wb + (size_t)(n0 + lrB) * H_DIM + lqB * 8;

    f32x4 acc0 = {0.f, 0.f, 0.f, 0.f};
    f32x4 acc1 = {0.f, 0.f, 0.f, 0.f};

    const int row = lane & 15;
    const int q = lane >> 4;

    // stage tile 0 into buffer 0
    uint4 av0 = *(const uint4*)(ap);
    uint4 av1 = *(const uint4*)(ap + 8);
    uint4 bv  = *(const uint4*)(bp);
    *(uint4*)&As[0][lrA][lqA * 16]     = av0;
    *(uint4*)&As[0][lrA][lqA * 16 + 8] = av1;
    *(uint4*)&Ws[0][lrB][lqB * 8]      = bv;
    __syncthreads();

    for (int ki = 0; ki < 32; ++ki) {
        const int cur = ki & 1, nxt = cur ^ 1;
        if (ki + 1 < 32) {  // prefetch next tile into registers
            av0 = *(const uint4*)(ap + (ki + 1) * 64);
            av1 = *(const uint4*)(ap + (ki + 1) * 64 + 8);
            bv  = *(const uint4*)(bp + (ki + 1) * 64);
        }
        #pragma unroll
        for (int ks = 0; ks < 2; ++ks) {
            bf16x8 a0 = *(const bf16x8*)&As[cur][wm + row][ks * 32 + q * 8];
            bf16x8 a1 = *(const bf16x8*)&As[cur][wm + 16 + row][ks * 32 + q * 8];
            bf16x8 b0 = *(const bf16x8*)&Ws[cur][wn + row][ks * 32 + q * 8];
            acc0 = __builtin_amdgcn_mfma_f32_16x16x32_bf16(a0, b0, acc0, 0, 0, 0);
            acc1 = __builtin_amdgcn_mfma_f32_16x16x32_bf16(a1, b0, acc1, 0, 0, 0);
        }
        if (ki + 1 < 32) {  // write next tile into the other buffer
            *(uint4*)&As[nxt][lrA][lqA * 16]     = av0;
            *(uint4*)&As[nxt][lrA][lqA * 16 + 8] = av1;
            *(uint4*)&Ws[nxt][lrB][lqB * 8]      = bv;
        }
        __syncthreads();
    }

    // D mapping: col=lane&15, row=(lane>>4)*4+reg
    const int col = lane & 15;
    const float bias0 = bias[n0 + wn + col];
    #pragma unroll
    for (int r = 0; r < 4; ++r) {
        const int mr = q * 4 + r;
        float* o0 = out + (size_t)(m0 + wm + mr) * H_DIM + n0 + wn;
        float* o1 = out + (size_t)(m0 + wm + 16 + mr) * H_DIM + n0 + wn;
        o0[col] = acc0[r] + bias0;
        o1[col] = acc1[r] + bias0;
    }
}

extern "C" void kernel_launch(void* const* d_in, const int* in_sizes, int n_in,
                              void* d_out, int out_size, void* d_ws, size_t ws_size,
                              hipStream_t stream) {
    const float* OG   = (const float*)d_in[0];
    const float* E    = (const float*)d_in[1];
    const float* W    = (const float*)d_in[2];
    const float* bias = (const float*)d_in[3];
    float* out = (float*)d_out;

    unsigned short* wrep = (unsigned short*)d_ws;                 // 2 MiB bf16
    unsigned short* Wb   = wrep + (size_t)B_DIM * H_DIM;          // 8 MiB bf16

    simwrep_kernel<<<B_DIM, 512, 0, stream>>>(OG, E, W, wrep, Wb);
    gemm_kernel<<<dim3(H_DIM / 32, B_DIM / 64), 256, 0, stream>>>(wrep, Wb, bias, out);
}